// Round 3
// baseline (445.354 us; speedup 1.0000x reference)
//
#include <hip/hip_runtime.h>
#include <hip/hip_bf16.h>

typedef unsigned short u16;
typedef __bf16 bf16x8 __attribute__((ext_vector_type(8)));
typedef u16 u16x4 __attribute__((ext_vector_type(4)));
typedef u16 u16x8 __attribute__((ext_vector_type(8)));
typedef float f32x4 __attribute__((ext_vector_type(4)));
typedef float f32x16 __attribute__((ext_vector_type(16)));

#define S_LEN  2048
#define HID    4096
#define NHEADS 32
#define NKV    8
#define HD     128
#define QDIM   (NHEADS*HD)   // 4096
#define KVDIM  (NKV*HD)      // 1024

__device__ __forceinline__ u16 f2bf(float f) {
  unsigned u = __float_as_uint(f);
  u += 0x7fff + ((u >> 16) & 1);   // RNE
  return (u16)(u >> 16);
}
__device__ __forceinline__ void lds_load16(const u16* g, u16* l) {
  __builtin_amdgcn_global_load_lds(
      (__attribute__((address_space(1))) void*)(g),
      (__attribute__((address_space(3))) void*)(l), 16, 0, 0);
}

// ---------------------------------------------------------------------------
// Segmented fp32 -> bf16 bulk convert: 4 buffers in one launch. n = elems/8.
// ---------------------------------------------------------------------------
__global__ __launch_bounds__(256) void f2b4(
    const float* __restrict__ s0, u16* __restrict__ d0, long n0,
    const float* __restrict__ s1, u16* __restrict__ d1, long n1,
    const float* __restrict__ s2, u16* __restrict__ d2, long n2,
    const float* __restrict__ s3, u16* __restrict__ d3, long n3)
{
  const float* s; u16* d; long n; int b0, nb;
  const int b = blockIdx.x;
  if (b < 1024)      { s=s0; d=d0; n=n0; b0=0;    nb=1024; }
  else if (b < 3072) { s=s1; d=d1; n=n1; b0=1024; nb=2048; }
  else if (b < 3584) { s=s2; d=d2; n=n2; b0=3072; nb=512;  }
  else               { s=s3; d=d3; n=n3; b0=3584; nb=512;  }
  long i = (long)(b - b0)*256 + threadIdx.x;
  const long stride = (long)nb*256;
  for (; i < n; i += stride) {
    f32x4 a = ((const f32x4*)s)[i*2];
    f32x4 c = ((const f32x4*)s)[i*2 + 1];
    u16x8 o;
    #pragma unroll
    for (int j = 0; j < 4; ++j) { o[j] = f2bf(a[j]); o[4+j] = f2bf(c[j]); }
    ((u16x8*)d)[i] = o;
  }
}

__global__ __launch_bounds__(256) void f2b(
    const float* __restrict__ in, u16* __restrict__ out, long n8)
{
  long i = (long)blockIdx.x * blockDim.x + threadIdx.x;
  const long stride = (long)gridDim.x * blockDim.x;
  for (; i < n8; i += stride) {
    f32x4 a = ((const f32x4*)in)[i*2];
    f32x4 b = ((const f32x4*)in)[i*2 + 1];
    u16x8 o;
    #pragma unroll
    for (int j = 0; j < 4; ++j) { o[j] = f2bf(a[j]); o[4+j] = f2bf(b[j]); }
    ((u16x8*)out)[i] = o;
  }
}

// ---------------------------------------------------------------------------
// 256x256-tile 4-phase/K-tile GEMM (QKV projection), C = A[M,K]*B[N,K]^T.
// BK=64, 8 waves 2Mx4N, acc[8][4], counted vmcnt(6), G4 XOR swizzle.
// ---------------------------------------------------------------------------
template<int CMODE>
__global__ __launch_bounds__(512, 2) void gemm8(
    const u16* __restrict__ A, const u16* __restrict__ B,
    void* __restrict__ Cq, void* __restrict__ Ck, void* __restrict__ Cv,
    int M, int N, int K)
{
  __shared__ u16 lds[65536];   // [0,32768): A  [32768,65536): B
  const int tid  = threadIdx.x;
  const int lane = tid & 63;
  const int w    = tid >> 6;
  const int wr   = w >> 2, wc = w & 3;
  const int l16  = lane & 15, lhi = lane >> 4;
  const long arow0 = (long)blockIdx.y * 256;
  const long brow0 = (long)blockIdx.x * 256;
  const int ntiles = K >> 6;

  const u16* Ag[2]; const u16* Bg[2];
  #pragma unroll
  for (int r = 0; r < 2; ++r) {
    const int p  = r*4096 + w*512 + lane*8;
    const int lr = p >> 6;
    const int cu = (p & 63) ^ ((lr & 7) << 3);
    Ag[r] = A + (arow0 + (lr >> 6)*128 + (lr & 63))*(long)K + cu;
    Bg[r] = B + (brow0 + (lr >> 5)*64  + (lr & 31))*(long)K + cu;
  }
  u16* const dstA = lds + w*512;
  u16* const dstB = lds + 32768 + w*512;

  auto stageA = [&](int s, int kt) {
    const long so = (long)(kt*64) + (long)(s*64)*K;
    u16* d = dstA + (((kt & 1)*2 + s) << 13);
    lds_load16(Ag[0] + so, d);
    lds_load16(Ag[1] + so, d + 4096);
  };
  auto stageB = [&](int s, int kt) {
    const long so = (long)(kt*64) + (long)(s*32)*K;
    u16* d = dstB + (((kt & 1)*2 + s) << 13);
    lds_load16(Bg[0] + so, d);
    lds_load16(Bg[1] + so, d + 4096);
  };

  const int xr = (l16 & 7) << 3;
  int offA[4][2], offB[2][2];
  #pragma unroll
  for (int m2 = 0; m2 < 4; ++m2)
    #pragma unroll
    for (int ks = 0; ks < 2; ++ks)
      offA[m2][ks] = (wr*64 + m2*16 + l16)*64 + ((ks*32 + lhi*8) ^ xr);
  #pragma unroll
  for (int n2 = 0; n2 < 2; ++n2)
    #pragma unroll
    for (int ks = 0; ks < 2; ++ks)
      offB[n2][ks] = (wc*32 + n2*16 + l16)*64 + ((ks*32 + lhi*8) ^ xr);

  f32x4 acc[8][4] = {};

  stageA(0, 0); stageB(0, 0); stageB(1, 0); stageA(1, 0);
  stageA(0, 1); stageB(0, 1); stageB(1, 1);
  asm volatile("s_waitcnt vmcnt(6)" ::: "memory");
  __builtin_amdgcn_s_barrier();

  #pragma unroll 2
  for (int t = 0; t < ntiles; ++t) {
    const int Ab = (t & 1) << 14;
    const int Bb = 32768 + ((t & 1) << 14);
    bf16x8 af[4][2], bf[2][2], af2[4][2], bf2[2][2];

    // ---------- phase 1 ----------
    #pragma unroll
    for (int m2 = 0; m2 < 4; ++m2)
      #pragma unroll
      for (int ks = 0; ks < 2; ++ks)
        af[m2][ks] = *(const bf16x8*)(lds + Ab + offA[m2][ks]);
    #pragma unroll
    for (int n2 = 0; n2 < 2; ++n2)
      #pragma unroll
      for (int ks = 0; ks < 2; ++ks)
        bf[n2][ks] = *(const bf16x8*)(lds + Bb + offB[n2][ks]);
    if (t + 1 < ntiles) stageA(1, t + 1);
    __builtin_amdgcn_s_barrier();
    asm volatile("s_waitcnt lgkmcnt(0)" ::: "memory");
    __builtin_amdgcn_s_setprio(1);
    #pragma unroll
    for (int m2 = 0; m2 < 4; ++m2)
      #pragma unroll
      for (int n2 = 0; n2 < 2; ++n2)
        #pragma unroll
        for (int ks = 0; ks < 2; ++ks)
          acc[m2][n2] = __builtin_amdgcn_mfma_f32_16x16x32_bf16(
              af[m2][ks], bf[n2][ks], acc[m2][n2], 0, 0, 0);
    __builtin_amdgcn_s_setprio(0);
    __builtin_amdgcn_s_barrier();

    // ---------- phase 2 ----------
    #pragma unroll
    for (int n2 = 0; n2 < 2; ++n2)
      #pragma unroll
      for (int ks = 0; ks < 2; ++ks)
        bf2[n2][ks] = *(const bf16x8*)(lds + Bb + 8192 + offB[n2][ks]);
    if (t + 2 < ntiles) stageA(0, t + 2);
    __builtin_amdgcn_s_barrier();
    asm volatile("s_waitcnt lgkmcnt(0)" ::: "memory");
    __builtin_amdgcn_s_setprio(1);
    #pragma unroll
    for (int m2 = 0; m2 < 4; ++m2)
      #pragma unroll
      for (int n2 = 0; n2 < 2; ++n2)
        #pragma unroll
        for (int ks = 0; ks < 2; ++ks)
          acc[m2][2+n2] = __builtin_amdgcn_mfma_f32_16x16x32_bf16(
              af[m2][ks], bf2[n2][ks], acc[m2][2+n2], 0, 0, 0);
    __builtin_amdgcn_s_setprio(0);
    __builtin_amdgcn_s_barrier();

    // ---------- phase 3 ----------
    #pragma unroll
    for (int m2 = 0; m2 < 4; ++m2)
      #pragma unroll
      for (int ks = 0; ks < 2; ++ks)
        af2[m2][ks] = *(const bf16x8*)(lds + Ab + 8192 + offA[m2][ks]);
    if (t + 2 < ntiles) stageB(0, t + 2);
    __builtin_amdgcn_s_barrier();
    asm volatile("s_waitcnt lgkmcnt(0)" ::: "memory");
    __builtin_amdgcn_s_setprio(1);
    #pragma unroll
    for (int m2 = 0; m2 < 4; ++m2)
      #pragma unroll
      for (int n2 = 0; n2 < 2; ++n2)
        #pragma unroll
        for (int ks = 0; ks < 2; ++ks)
          acc[4+m2][2+n2] = __builtin_amdgcn_mfma_f32_16x16x32_bf16(
              af2[m2][ks], bf2[n2][ks], acc[4+m2][2+n2], 0, 0, 0);
    __builtin_amdgcn_s_setprio(0);
    __builtin_amdgcn_s_barrier();

    // ---------- phase 4 ----------
    if (t + 2 < ntiles) stageB(1, t + 2);
    __builtin_amdgcn_s_barrier();
    __builtin_amdgcn_s_setprio(1);
    #pragma unroll
    for (int m2 = 0; m2 < 4; ++m2)
      #pragma unroll
      for (int n2 = 0; n2 < 2; ++n2)
        #pragma unroll
        for (int ks = 0; ks < 2; ++ks)
          acc[4+m2][n2] = __builtin_amdgcn_mfma_f32_16x16x32_bf16(
              af2[m2][ks], bf[n2][ks], acc[4+m2][n2], 0, 0, 0);
    __builtin_amdgcn_s_setprio(0);
    if (t + 2 < ntiles) { asm volatile("s_waitcnt vmcnt(6)" ::: "memory"); }
    else                { asm volatile("s_waitcnt vmcnt(0)" ::: "memory"); }
    __builtin_amdgcn_s_barrier();
  }

  #pragma unroll
  for (int m = 0; m < 8; ++m) {
    const long row = arow0 + wr*128 + m*16 + lhi*4;
    #pragma unroll
    for (int n = 0; n < 4; ++n) {
      const long col = brow0 + wc*64 + n*16 + l16;
      if (CMODE == 1) {
        #pragma unroll
        for (int r = 0; r < 4; ++r)
          ((float*)Cq)[(row + r)*N + col] = acc[m][n][r];
      } else {  // CMODE 3: fused QKV
        if (blockIdx.x < 16) {
          #pragma unroll
          for (int r = 0; r < 4; ++r)
            ((u16*)Cq)[(row + r)*QDIM + col] = f2bf(acc[m][n][r]);
        } else if (blockIdx.x < 20) {
          #pragma unroll
          for (int r = 0; r < 4; ++r)
            ((u16*)Ck)[(row + r)*KVDIM + (col - QDIM)] = f2bf(acc[m][n][r]);
        } else {
          u16x4 o;
          #pragma unroll
          for (int r = 0; r < 4; ++r) o[r] = f2bf(acc[m][n][r]);
          *(u16x4*)((u16*)Cv + (col - QDIM - KVDIM)*(long)S_LEN + row) = o;
        }
      }
    }
  }
}

// ---------------------------------------------------------------------------
// 128x256-tile 4-phase GEMM for the final projection (unchanged, verified).
// ---------------------------------------------------------------------------
__global__ __launch_bounds__(512, 2) void gemmF(
    const u16* __restrict__ A, const u16* __restrict__ B,
    float* __restrict__ C, int M, int N, int K)
{
  __shared__ u16 lds[49152];   // A: [0,16384) 2x8192; B: [16384,49152) 2x16384
  const int tid  = threadIdx.x;
  const int lane = tid & 63;
  const int w    = tid >> 6;
  const int wr   = w >> 2, wc = w & 3;
  const int l16  = lane & 15, lhi = lane >> 4;
  const long arow0 = (long)blockIdx.y * 128;
  const long brow0 = (long)blockIdx.x * 256;
  const int ntiles = K >> 6;

  const int cu = ((lane & 7) ^ (lane >> 3)) * 8;
  const int rA  = (w >> 2)*64 + (w & 3)*8;
  const int rB1c = 128 + (w >> 2)*64 + (w & 3)*8;
  const u16* srcA  = A + (arow0 + rA   + (lane >> 3))*(long)K + cu;
  const u16* srcB0 = B + (brow0 + rA   + (lane >> 3))*(long)K + cu;
  const u16* srcB1 = B + (brow0 + rB1c + (lane >> 3))*(long)K + cu;
  u16* const dA  = lds + rA*64;
  u16* const dB0 = lds + 16384 + rA*64;
  u16* const dB1 = lds + 16384 + rB1c*64;

  auto stageA = [&](int s, int kt) {
    lds_load16(srcA + (long)(s*32)*K + kt*64,
               dA + ((kt & 1) << 13) + s*2048);
  };
  auto stageB = [&](int s, int kt) {
    const long so = (long)(s*32)*K + kt*64;
    const int  d  = ((kt & 1) << 14) + s*2048;
    lds_load16(srcB0 + so, dB0 + d);
    lds_load16(srcB1 + so, dB1 + d);
  };

  const int xr = (l16 & 7) << 3;
  int offA[2][2], offB[2][2];
  #pragma unroll
  for (int m = 0; m < 2; ++m)
    #pragma unroll
    for (int ks = 0; ks < 2; ++ks)
      offA[m][ks] = (wr*64 + m*16 + l16)*64 + ((ks*32 + lhi*8) ^ xr);
  #pragma unroll
  for (int n = 0; n < 2; ++n)
    #pragma unroll
    for (int ks = 0; ks < 2; ++ks)
      offB[n][ks] = (wc*64 + n*16 + l16)*64 + ((ks*32 + lhi*8) ^ xr);

  f32x4 acc[4][4] = {};

  stageA(0, 0); stageA(1, 0); stageB(0, 0); stageB(1, 0);
  if (ntiles > 1) { stageA(0, 1); stageB(0, 1); stageB(1, 1); }
  asm volatile("s_waitcnt vmcnt(5)" ::: "memory");
  __builtin_amdgcn_s_barrier();

  #pragma unroll 2
  for (int t = 0; t < ntiles; ++t) {
    const int Ab = (t & 1) << 13;
    const int Bb = 16384 + ((t & 1) << 14);
    bf16x8 af[2][2], bf[2][2], af2[2][2], bf2[2][2];

    // ---------- phase 1 ----------
    #pragma unroll
    for (int m = 0; m < 2; ++m)
      #pragma unroll
      for (int ks = 0; ks < 2; ++ks)
        af[m][ks] = *(const bf16x8*)(lds + Ab + offA[m][ks]);
    #pragma unroll
    for (int n = 0; n < 2; ++n)
      #pragma unroll
      for (int ks = 0; ks < 2; ++ks)
        bf[n][ks] = *(const bf16x8*)(lds + Bb + offB[n][ks]);
    if (t + 1 < ntiles) stageA(1, t + 1);
    __builtin_amdgcn_s_barrier();
    asm volatile("s_waitcnt lgkmcnt(0)" ::: "memory");
    __builtin_amdgcn_s_setprio(1);
    #pragma unroll
    for (int m = 0; m < 2; ++m)
      #pragma unroll
      for (int n = 0; n < 2; ++n)
        #pragma unroll
        for (int ks = 0; ks < 2; ++ks)
          acc[m][n] = __builtin_amdgcn_mfma_f32_16x16x32_bf16(
              af[m][ks], bf[n][ks], acc[m][n], 0, 0, 0);
    __builtin_amdgcn_s_setprio(0);
    __builtin_amdgcn_s_barrier();

    // ---------- phase 2 ----------
    #pragma unroll
    for (int n = 0; n < 2; ++n)
      #pragma unroll
      for (int ks = 0; ks < 2; ++ks)
        bf2[n][ks] = *(const bf16x8*)(lds + Bb + 2048 + offB[n][ks]);
    if (t + 2 < ntiles) stageA(0, t + 2);
    __builtin_amdgcn_s_barrier();
    asm volatile("s_waitcnt lgkmcnt(0)" ::: "memory");
    __builtin_amdgcn_s_setprio(1);
    #pragma unroll
    for (int m = 0; m < 2; ++m)
      #pragma unroll
      for (int n = 0; n < 2; ++n)
        #pragma unroll
        for (int ks = 0; ks < 2; ++ks)
          acc[m][2+n] = __builtin_amdgcn_mfma_f32_16x16x32_bf16(
              af[m][ks], bf2[n][ks], acc[m][2+n], 0, 0, 0);
    __builtin_amdgcn_s_setprio(0);
    __builtin_amdgcn_s_barrier();

    // ---------- phase 3 ----------
    #pragma unroll
    for (int m = 0; m < 2; ++m)
      #pragma unroll
      for (int ks = 0; ks < 2; ++ks)
        af2[m][ks] = *(const bf16x8*)(lds + Ab + 2048 + offA[m][ks]);
    if (t + 2 < ntiles) stageB(0, t + 2);
    __builtin_amdgcn_s_barrier();
    asm volatile("s_waitcnt lgkmcnt(0)" ::: "memory");
    __builtin_amdgcn_s_setprio(1);
    #pragma unroll
    for (int m = 0; m < 2; ++m)
      #pragma unroll
      for (int n = 0; n < 2; ++n)
        #pragma unroll
        for (int ks = 0; ks < 2; ++ks)
          acc[2+m][2+n] = __builtin_amdgcn_mfma_f32_16x16x32_bf16(
              af2[m][ks], bf2[n][ks], acc[2+m][2+n], 0, 0, 0);
    __builtin_amdgcn_s_setprio(0);
    __builtin_amdgcn_s_barrier();

    // ---------- phase 4 ----------
    if (t + 2 < ntiles) stageB(1, t + 2);
    __builtin_amdgcn_s_barrier();
    __builtin_amdgcn_s_setprio(1);
    #pragma unroll
    for (int m = 0; m < 2; ++m)
      #pragma unroll
      for (int n = 0; n < 2; ++n)
        #pragma unroll
        for (int ks = 0; ks < 2; ++ks)
          acc[2+m][n] = __builtin_amdgcn_mfma_f32_16x16x32_bf16(
              af2[m][ks], bf[n][ks], acc[2+m][n], 0, 0, 0);
    __builtin_amdgcn_s_setprio(0);
    if (t + 2 < ntiles) { asm volatile("s_waitcnt vmcnt(5)" ::: "memory"); }
    else                { asm volatile("s_waitcnt vmcnt(0)" ::: "memory"); }
    __builtin_amdgcn_s_barrier();
  }

  #pragma unroll
  for (int mi = 0; mi < 4; ++mi) {
    const long row = arow0 + wr*64 + (mi >> 1)*32 + (mi & 1)*16 + lhi*4;
    #pragma unroll
    for (int ni = 0; ni < 4; ++ni) {
      const long col = brow0 + wc*64 + (ni >> 1)*32 + (ni & 1)*16 + l16;
      #pragma unroll
      for (int r = 0; r < 4; ++r)
        C[(row + r)*N + col] = acc[mi][ni][r];
    }
  }
}

// ---------------------------------------------------------------------------
// Fused per-head RMSNorm + RoPE for BOTH Q and K in one launch, in place.
// ---------------------------------------------------------------------------
__global__ __launch_bounds__(256) void norm_rope2(
    u16* __restrict__ Qb, u16* __restrict__ Kb,
    const float* __restrict__ qw, const float* __restrict__ kw,
    const int* __restrict__ pos)
{
  const int row  = blockIdx.x * 4 + (threadIdx.x >> 6);
  const int lane = threadIdx.x & 63;
  u16* p; const float* nw; float sc; int s;
  if (row < S_LEN*NHEADS) {
    p = Qb + (long)row * HD; nw = qw; sc = 0.08838834764831845f; s = row >> 5;
  } else {
    const int r2 = row - S_LEN*NHEADS;
    p = Kb + (long)r2 * HD; nw = kw; sc = 1.0f; s = r2 >> 3;
  }

  float x1 = __uint_as_float(((unsigned)p[lane]) << 16);
  float x2 = __uint_as_float(((unsigned)p[lane + 64]) << 16);
  float ss = x1*x1 + x2*x2;
  #pragma unroll
  for (int m = 32; m >= 1; m >>= 1) ss += __shfl_xor(ss, m);
  const float inv = rsqrtf(ss * (1.0f/128.0f) + 1e-6f);
  x1 *= inv * nw[lane];
  x2 *= inv * nw[lane + 64];

  const float inv_freq = expf(-(float)lane * (13.815510557964274f / 64.0f));
  const float ang = (float)pos[s] * inv_freq;
  float sn, cs;
  sincosf(ang, &sn, &cs);
  p[lane]      = f2bf((x1*cs - x2*sn) * sc);
  p[lane + 64] = f2bf((x2*cs + x1*sn) * sc);
}

// ---------------------------------------------------------------------------
// Causal flash attention, 32x32x16 MFMA. One 128-row q-tile per block,
// 4 waves x 32 q-rows. KVBLK=64. Single-buffered K/V (round-1 flow; 48KB LDS,
// 2-3 blocks/CU). Per wave-tile: QK^T = 16 mfma (B-reads halved vs 16x16),
// softmax fully per-reg (reduce = 5 shfl_xor within 32-lane halves),
// P via LDS, PV = 16 mfma. Fully-masked kv-tiles skipped per-wave.
// C/D layout (m74/m101): col=lane&31, row=(reg&3)+8*(reg>>2)+4*(lane>>5).
// A/B frag: k = (lane>>5)*8 + j (2 groups of 8 = K16), row/col = lane&31.
// ---------------------------------------------------------------------------
__global__ __launch_bounds__(256, 2) void attn(
    const u16* __restrict__ Q, const u16* __restrict__ K,
    const u16* __restrict__ VT, u16* __restrict__ O)
{
  __shared__ u16 Ks[64*128];   // [kv][d], XOR-swizzled cols
  __shared__ u16 Vt[128*64];   // [d][kv], XOR-swizzled cols
  __shared__ u16 Ps[4][32*64]; // per-wave P [q][kv], XOR-swizzled cols

  const int tid  = threadIdx.x;
  const int lane = tid & 63;
  const int w    = tid >> 6;
  const int l16  = lane & 15, lhi = lane >> 4;   // staging decomposition
  const int l32  = lane & 31, lh  = lane >> 5;   // mfma decomposition
  const int h    = blockIdx.y;
  const int kh   = h >> 2;                       // GQA 4:1
  const int Tq   = 15 - ((blockIdx.x + blockIdx.y) & 15);
  const int qrow0 = Tq*128 + w*32;
  const int ntile = 2*Tq + 2;

  // Q fragments: lane holds Q[qrow0+l32][s*16 + lh*8 + j]
  bf16x8 qf[8];
  #pragma unroll
  for (int s = 0; s < 8; ++s)
    qf[s] = *(const bf16x8*)(Q + (long)(qrow0 + l32)*QDIM + h*HD + s*16 + lh*8);

  float mr[16], lr[16];
  #pragma unroll
  for (int r = 0; r < 16; ++r) { mr[r] = -1e30f; lr[r] = 0.f; }
  f32x16 of[4] = {};
  u16* Pw = Ps[w];

  for (int t = 0; t < ntile; ++t) {
    const int kv0 = t * 64;
    // stage K tile [64][128]
    #pragma unroll
    for (int i = 0; i < 4; ++i) {
      const int r   = w*16 + i*4 + lhi;
      const int col = (l16*8) ^ ((r & 7) << 3);
      lds_load16(K + (long)(kv0 + r)*KVDIM + kh*HD + col,
                 Ks + (w*16 + i*4)*128);
    }
    // stage V^T tile [128][64]
    #pragma unroll
    for (int i = 0; i < 4; ++i) {
      const int r   = w*32 + i*8 + (lane >> 3);
      const int col = ((lane & 7)*8) ^ ((r & 7) << 3);
      lds_load16(VT + (long)(kh*HD + r)*S_LEN + kv0 + col,
                 Vt + (w*32 + i*8)*64);
    }
    __syncthreads();

    if (kv0 <= qrow0 + 31) {   // wave-uniform: skip fully-masked tiles
      // ---- QK^T: out P[32q][64kv] as 2 tiles of 32x32 ----
      f32x16 sa[2] = {};
      __builtin_amdgcn_s_setprio(1);
      #pragma unroll
      for (int s = 0; s < 8; ++s) {
        const int dco = (s*16 + lh*8);
        #pragma unroll
        for (int n = 0; n < 2; ++n) {
          bf16x8 kf = *(const bf16x8*)(
              Ks + (n*32 + l32)*128 + (dco ^ ((l32 & 7) << 3)));
          sa[n] = __builtin_amdgcn_mfma_f32_32x32x16_bf16(
              qf[s], kf, sa[n], 0, 0, 0);
        }
      }
      __builtin_amdgcn_s_setprio(0);

      // ---- causal mask ----
      const bool diag = (kv0 + 63 > qrow0);
      if (diag) {
        #pragma unroll
        for (int n = 0; n < 2; ++n)
          #pragma unroll
          for (int r = 0; r < 16; ++r) {
            const int q  = qrow0 + (r & 3) + 8*(r >> 2) + 4*lh;
            const int kv = kv0 + n*32 + l32;
            if (kv > q) sa[n][r] = -1e9f;
          }
      }

      // ---- per-row max (reduce over 32-lane halves) ----
      float mx[16];
      #pragma unroll
      for (int r = 0; r < 16; ++r) {
        float m2 = fmaxf(sa[0][r], sa[1][r]);
        m2 = fmaxf(m2, __shfl_xor(m2, 1));
        m2 = fmaxf(m2, __shfl_xor(m2, 2));
        m2 = fmaxf(m2, __shfl_xor(m2, 4));
        m2 = fmaxf(m2, __shfl_xor(m2, 8));
        m2 = fmaxf(m2, __shfl_xor(m2, 16));
        mx[r] = m2;
      }
      // ---- defer-max rescale (THR=8) ----
      bool need = false;
      #pragma unroll
      for (int r = 0; r < 16; ++r) need |= (mx[r] > mr[r] + 8.f);
      if (__any(need)) {
        #pragma unroll
        for (int r = 0; r < 16; ++r) {
          const float mnew  = fmaxf(mr[r], mx[r]);
          const float alpha = __expf(mr[r] - mnew);
          mr[r] = mnew;
          lr[r] *= alpha;
          #pragma unroll
          for (int dt = 0; dt < 4; ++dt) of[dt][r] *= alpha;
        }
      }
      // ---- exp + row sum ----
      #pragma unroll
      for (int r = 0; r < 16; ++r) {
        float p0 = __expf(sa[0][r] - mr[r]);
        float p1 = __expf(sa[1][r] - mr[r]);
        sa[0][r] = p0; sa[1][r] = p1;
        float rs = p0 + p1;
        rs += __shfl_xor(rs, 1);
        rs += __shfl_xor(rs, 2);
        rs += __shfl_xor(rs, 4);
        rs += __shfl_xor(rs, 8);
        rs += __shfl_xor(rs, 16);
        lr[r] += rs;
      }

      // ---- P -> LDS (per-wave region) ----
      #pragma unroll
      for (int n = 0; n < 2; ++n)
        #pragma unroll
        for (int r = 0; r < 16; ++r) {
          const int qr = (r & 3) + 8*(r >> 2) + 4*lh;
          Pw[qr*64 + ((n*32 + l32) ^ ((qr & 7) << 3))] = f2bf(sa[n][r]);
        }

      // ---- PV: O[32q][128d] as 4 tiles of 32x32, k over 64 kv ----
      __builtin_amdgcn_s_setprio(1);
      #pragma unroll
      for (int ks = 0; ks < 4; ++ks) {
        const int kco = (ks*16 + lh*8);
        bf16x8 pf = *(const bf16x8*)(
            Pw + l32*64 + (kco ^ ((l32 & 7) << 3)));
        #pragma unroll
        for (int dt = 0; dt < 4; ++dt) {
          bf16x8 vf = *(const bf16x8*)(
              Vt + (dt*32 + l32)*64 + (kco ^ ((l32 & 7) << 3)));
          of[dt] = __builtin_amdgcn_mfma_f32_32x32x16_bf16(
              pf, vf, of[dt], 0, 0, 0);
        }
      }
      __builtin_amdgcn_s_setprio(0);
    }
    __syncthreads();
  }

  // ---- epilogue ----
  #pragma unroll
  for (int r = 0; r < 16; ++r) {
    const int qr = (r & 3) + 8*(r >> 2) + 4*lh;
    const float invl = 1.0f / lr[r];
    const long orow = (long)(qrow0 + qr)*QDIM + h*HD;
    #pragma unroll
    for (int dt = 0; dt < 4; ++dt)
      O[orow + dt*32 + l32] = f2bf(of[dt][r] * invl);
  }
}

// ---------------------------------------------------------------------------
extern "C" void kernel_launch(void* const* d_in, const int* in_sizes, int n_in,
                              void* d_out, int out_size, void* d_ws, size_t ws_size,
                              hipStream_t stream) {
  (void)in_sizes; (void)n_in; (void)out_size; (void)ws_size;
  const float* hs  = (const float*)d_in[0];
  const int*   pos = (const int*)d_in[1];
  const float* Wq  = (const float*)d_in[2];
  const float* Wk  = (const float*)d_in[3];
  const float* Wv  = (const float*)d_in[4];
  const float* Wo  = (const float*)d_in[5];
  const float* qw  = (const float*)d_in[6];
  const float* kw  = (const float*)d_in[7];

  // Workspace layout (bf16 u16 elements), total 88 MB:
  u16* hsB = (u16*)d_ws;                          // 2048*4096
  u16* W1  = hsB + (long)S_LEN*HID;               // 4096*4096 (Wq, later Wo)
  u16* WkB = W1  + (long)QDIM*HID;                // 1024*4096 (contiguous!)
  u16* WvB = WkB + (long)KVDIM*HID;               // 1024*4096 (contiguous!)
  u16* Kb  = WvB + (long)KVDIM*HID;               // 2048*1024
  u16* VT  = Kb  + (long)S_LEN*KVDIM;             // 1024*2048 (V transposed)
  u16* AO  = VT  + (long)KVDIM*S_LEN;             // 2048*4096
  u16* Qb  = (u16*)d_out;                         // 2048*4096 (dead before final GEMM)

  f2b4<<<4096, 256, 0, stream>>>(hs, hsB, (long)S_LEN*HID/8,
                                 Wq, W1,  (long)QDIM*HID/8,
                                 Wk, WkB, (long)KVDIM*HID/8,
                                 Wv, WvB, (long)KVDIM*HID/8);

  // fused Q+K+V projection: B = [Wq; Wk; Wv] (6144 rows), 24x8 = 192 blocks
  gemm8<3><<<dim3((QDIM+2*KVDIM)/256, S_LEN/256), 512, 0, stream>>>(
      hsB, W1, Qb, Kb, VT, S_LEN, QDIM+2*KVDIM, HID);

  norm_rope2<<<(S_LEN*NHEADS + S_LEN*NKV)/4, 256, 0, stream>>>(
      Qb, Kb, qw, kw, pos);

  f2b<<<2048, 256, 0, stream>>>(Wo, W1, (long)HID*QDIM/8);

  // attention: 16 q-tiles (128 rows) x 32 heads = 512 blocks
  attn<<<dim3(16, NHEADS), 256, 0, stream>>>(Qb, Kb, VT, AO);

  // final projection: 128x256 tile, 16x16 = 256 blocks (full machine)
  gemmF<<<dim3(HID/256, S_LEN/128), 512, 0, stream>>>(
      AO, W1, (float*)d_out, S_LEN, HID, QDIM);
}

// Round 4
// 392.481 us; speedup vs baseline: 1.1347x; 1.1347x over previous
//
#include <hip/hip_runtime.h>
#include <hip/hip_bf16.h>

typedef unsigned short u16;
typedef __bf16 bf16x8 __attribute__((ext_vector_type(8)));
typedef u16 u16x4 __attribute__((ext_vector_type(4)));
typedef u16 u16x8 __attribute__((ext_vector_type(8)));
typedef float f32x4 __attribute__((ext_vector_type(4)));

#define S_LEN  2048
#define HID    4096
#define NHEADS 32
#define NKV    8
#define HD     128
#define QDIM   (NHEADS*HD)   // 4096
#define KVDIM  (NKV*HD)      // 1024
#define NT     (S_LEN/64)    // 32 kv/q tiles

__device__ __forceinline__ u16 f2bf(float f) {
  unsigned u = __float_as_uint(f);
  u += 0x7fff + ((u >> 16) & 1);   // RNE
  return (u16)(u >> 16);
}
__device__ __forceinline__ void lds_load16(const u16* g, u16* l) {
  __builtin_amdgcn_global_load_lds(
      (__attribute__((address_space(1))) void*)(g),
      (__attribute__((address_space(3))) void*)(l), 16, 0, 0);
}

// ---------------------------------------------------------------------------
// Segmented fp32 -> bf16 bulk convert: 4 buffers in one launch. n = elems/8.
// ---------------------------------------------------------------------------
__global__ __launch_bounds__(256) void f2b4(
    const float* __restrict__ s0, u16* __restrict__ d0, long n0,
    const float* __restrict__ s1, u16* __restrict__ d1, long n1,
    const float* __restrict__ s2, u16* __restrict__ d2, long n2,
    const float* __restrict__ s3, u16* __restrict__ d3, long n3)
{
  const float* s; u16* d; long n; int b0, nb;
  const int b = blockIdx.x;
  if (b < 1024)      { s=s0; d=d0; n=n0; b0=0;    nb=1024; }
  else if (b < 3072) { s=s1; d=d1; n=n1; b0=1024; nb=2048; }
  else if (b < 3584) { s=s2; d=d2; n=n2; b0=3072; nb=512;  }
  else               { s=s3; d=d3; n=n3; b0=3584; nb=512;  }
  long i = (long)(b - b0)*256 + threadIdx.x;
  const long stride = (long)nb*256;
  for (; i < n; i += stride) {
    f32x4 a = ((const f32x4*)s)[i*2];
    f32x4 c = ((const f32x4*)s)[i*2 + 1];
    u16x8 o;
    #pragma unroll
    for (int j = 0; j < 4; ++j) { o[j] = f2bf(a[j]); o[4+j] = f2bf(c[j]); }
    ((u16x8*)d)[i] = o;
  }
}

__global__ __launch_bounds__(256) void f2b(
    const float* __restrict__ in, u16* __restrict__ out, long n8)
{
  long i = (long)blockIdx.x * blockDim.x + threadIdx.x;
  const long stride = (long)gridDim.x * blockDim.x;
  for (; i < n8; i += stride) {
    f32x4 a = ((const f32x4*)in)[i*2];
    f32x4 b = ((const f32x4*)in)[i*2 + 1];
    u16x8 o;
    #pragma unroll
    for (int j = 0; j < 4; ++j) { o[j] = f2bf(a[j]); o[4+j] = f2bf(b[j]); }
    ((u16x8*)out)[i] = o;
  }
}

// ---------------------------------------------------------------------------
// 128x256-tile 4-phase GEMM, C = A[M,K]*B[N,K]^T. The structure verified as
// gemmF (rounds 2-3). 8 waves 2Mx4N, per-wave 64x64, acc[4][4]. LDS 96KB:
// A 2x8KB dbuf, B 2x32KB dbuf. Counted vmcnt(5). G4 XOR swizzle both-sides.
// CMODE 1: fp32 row-major C (final projection, grid 16x16=256).
// CMODE 3: fused QKV epilogue (grid 24x16=384): blockIdx.x<16 -> Q bf16,
//          <20 -> K bf16, else V^T bf16 (u16x4 contiguous stores).
// ---------------------------------------------------------------------------
template<int CMODE>
__global__ __launch_bounds__(512, 2) void gemmFX(
    const u16* __restrict__ A, const u16* __restrict__ B,
    void* __restrict__ Cq, void* __restrict__ Ck, void* __restrict__ Cv,
    int M, int N, int K)
{
  __shared__ u16 lds[49152];   // A: [0,16384) 2x8192; B: [16384,49152) 2x16384
  const int tid  = threadIdx.x;
  const int lane = tid & 63;
  const int w    = tid >> 6;
  const int wr   = w >> 2, wc = w & 3;
  const int l16  = lane & 15, lhi = lane >> 4;
  const long arow0 = (long)blockIdx.y * 128;
  const long brow0 = (long)blockIdx.x * 256;
  const int ntiles = K >> 6;

  const int cu = ((lane & 7) ^ (lane >> 3)) * 8;
  const int rA  = (w >> 2)*64 + (w & 3)*8;
  const int rB1c = 128 + (w >> 2)*64 + (w & 3)*8;
  const u16* srcA  = A + (arow0 + rA   + (lane >> 3))*(long)K + cu;
  const u16* srcB0 = B + (brow0 + rA   + (lane >> 3))*(long)K + cu;
  const u16* srcB1 = B + (brow0 + rB1c + (lane >> 3))*(long)K + cu;
  u16* const dA  = lds + rA*64;
  u16* const dB0 = lds + 16384 + rA*64;
  u16* const dB1 = lds + 16384 + rB1c*64;

  auto stageA = [&](int s, int kt) {
    lds_load16(srcA + (long)(s*32)*K + kt*64,
               dA + ((kt & 1) << 13) + s*2048);
  };
  auto stageB = [&](int s, int kt) {
    const long so = (long)(s*32)*K + kt*64;
    const int  d  = ((kt & 1) << 14) + s*2048;
    lds_load16(srcB0 + so, dB0 + d);
    lds_load16(srcB1 + so, dB1 + d);
  };

  const int xr = (l16 & 7) << 3;
  int offA[2][2], offB[2][2];
  #pragma unroll
  for (int m = 0; m < 2; ++m)
    #pragma unroll
    for (int ks = 0; ks < 2; ++ks)
      offA[m][ks] = (wr*64 + m*16 + l16)*64 + ((ks*32 + lhi*8) ^ xr);
  #pragma unroll
  for (int n = 0; n < 2; ++n)
    #pragma unroll
    for (int ks = 0; ks < 2; ++ks)
      offB[n][ks] = (wc*64 + n*16 + l16)*64 + ((ks*32 + lhi*8) ^ xr);

  f32x4 acc[4][4] = {};

  stageA(0, 0); stageA(1, 0); stageB(0, 0); stageB(1, 0);
  if (ntiles > 1) { stageA(0, 1); stageB(0, 1); stageB(1, 1); }
  asm volatile("s_waitcnt vmcnt(5)" ::: "memory");
  __builtin_amdgcn_s_barrier();

  #pragma unroll 2
  for (int t = 0; t < ntiles; ++t) {
    const int Ab = (t & 1) << 13;
    const int Bb = 16384 + ((t & 1) << 14);
    bf16x8 af[2][2], bf[2][2], af2[2][2], bf2[2][2];

    // ---------- phase 1: af x bf -> acc[0:2][0:2] ----------
    #pragma unroll
    for (int m = 0; m < 2; ++m)
      #pragma unroll
      for (int ks = 0; ks < 2; ++ks)
        af[m][ks] = *(const bf16x8*)(lds + Ab + offA[m][ks]);
    #pragma unroll
    for (int n = 0; n < 2; ++n)
      #pragma unroll
      for (int ks = 0; ks < 2; ++ks)
        bf[n][ks] = *(const bf16x8*)(lds + Bb + offB[n][ks]);
    if (t + 1 < ntiles) stageA(1, t + 1);
    __builtin_amdgcn_s_barrier();
    asm volatile("s_waitcnt lgkmcnt(0)" ::: "memory");
    __builtin_amdgcn_s_setprio(1);
    #pragma unroll
    for (int m = 0; m < 2; ++m)
      #pragma unroll
      for (int n = 0; n < 2; ++n)
        #pragma unroll
        for (int ks = 0; ks < 2; ++ks)
          acc[m][n] = __builtin_amdgcn_mfma_f32_16x16x32_bf16(
              af[m][ks], bf[n][ks], acc[m][n], 0, 0, 0);
    __builtin_amdgcn_s_setprio(0);
    __builtin_amdgcn_s_barrier();

    // ---------- phase 2: af x bf2 -> acc[0:2][2:4] ----------
    #pragma unroll
    for (int n = 0; n < 2; ++n)
      #pragma unroll
      for (int ks = 0; ks < 2; ++ks)
        bf2[n][ks] = *(const bf16x8*)(lds + Bb + 2048 + offB[n][ks]);
    if (t + 2 < ntiles) stageA(0, t + 2);
    __builtin_amdgcn_s_barrier();
    asm volatile("s_waitcnt lgkmcnt(0)" ::: "memory");
    __builtin_amdgcn_s_setprio(1);
    #pragma unroll
    for (int m = 0; m < 2; ++m)
      #pragma unroll
      for (int n = 0; n < 2; ++n)
        #pragma unroll
        for (int ks = 0; ks < 2; ++ks)
          acc[m][2+n] = __builtin_amdgcn_mfma_f32_16x16x32_bf16(
              af[m][ks], bf2[n][ks], acc[m][2+n], 0, 0, 0);
    __builtin_amdgcn_s_setprio(0);
    __builtin_amdgcn_s_barrier();

    // ---------- phase 3: af2 x bf2 -> acc[2:4][2:4] ----------
    #pragma unroll
    for (int m = 0; m < 2; ++m)
      #pragma unroll
      for (int ks = 0; ks < 2; ++ks)
        af2[m][ks] = *(const bf16x8*)(lds + Ab + 2048 + offA[m][ks]);
    if (t + 2 < ntiles) stageB(0, t + 2);
    __builtin_amdgcn_s_barrier();
    asm volatile("s_waitcnt lgkmcnt(0)" ::: "memory");
    __builtin_amdgcn_s_setprio(1);
    #pragma unroll
    for (int m = 0; m < 2; ++m)
      #pragma unroll
      for (int n = 0; n < 2; ++n)
        #pragma unroll
        for (int ks = 0; ks < 2; ++ks)
          acc[2+m][2+n] = __builtin_amdgcn_mfma_f32_16x16x32_bf16(
              af2[m][ks], bf2[n][ks], acc[2+m][2+n], 0, 0, 0);
    __builtin_amdgcn_s_setprio(0);
    __builtin_amdgcn_s_barrier();

    // ---------- phase 4: af2 x bf -> acc[2:4][0:2] ----------
    if (t + 2 < ntiles) stageB(1, t + 2);
    __builtin_amdgcn_s_barrier();
    __builtin_amdgcn_s_setprio(1);
    #pragma unroll
    for (int m = 0; m < 2; ++m)
      #pragma unroll
      for (int n = 0; n < 2; ++n)
        #pragma unroll
        for (int ks = 0; ks < 2; ++ks)
          acc[2+m][n] = __builtin_amdgcn_mfma_f32_16x16x32_bf16(
              af2[m][ks], bf[n][ks], acc[2+m][n], 0, 0, 0);
    __builtin_amdgcn_s_setprio(0);
    if (t + 2 < ntiles) { asm volatile("s_waitcnt vmcnt(5)" ::: "memory"); }
    else                { asm volatile("s_waitcnt vmcnt(0)" ::: "memory"); }
    __builtin_amdgcn_s_barrier();
  }

  // epilogue: C/D layout col = lane&15, row = (lane>>4)*4 + reg
  #pragma unroll
  for (int mi = 0; mi < 4; ++mi) {
    const long row = arow0 + wr*64 + (mi >> 1)*32 + (mi & 1)*16 + lhi*4;
    #pragma unroll
    for (int ni = 0; ni < 4; ++ni) {
      const long col = brow0 + wc*64 + (ni >> 1)*32 + (ni & 1)*16 + l16;
      if (CMODE == 1) {
        #pragma unroll
        for (int r = 0; r < 4; ++r)
          ((float*)Cq)[(row + r)*N + col] = acc[mi][ni][r];
      } else {  // CMODE 3: fused QKV
        if (blockIdx.x < 16) {
          #pragma unroll
          for (int r = 0; r < 4; ++r)
            ((u16*)Cq)[(row + r)*QDIM + col] = f2bf(acc[mi][ni][r]);
        } else if (blockIdx.x < 20) {
          #pragma unroll
          for (int r = 0; r < 4; ++r)
            ((u16*)Ck)[(row + r)*KVDIM + (col - QDIM)] = f2bf(acc[mi][ni][r]);
        } else {
          u16x4 o;
          #pragma unroll
          for (int r = 0; r < 4; ++r) o[r] = f2bf(acc[mi][ni][r]);
          *(u16x4*)((u16*)Cv + (col - QDIM - KVDIM)*(long)S_LEN + row) = o;
        }
      }
    }
  }
}

// ---------------------------------------------------------------------------
// Fused per-head RMSNorm + RoPE for BOTH Q and K in one launch, in place.
// ---------------------------------------------------------------------------
__global__ __launch_bounds__(256) void norm_rope2(
    u16* __restrict__ Qb, u16* __restrict__ Kb,
    const float* __restrict__ qw, const float* __restrict__ kw,
    const int* __restrict__ pos)
{
  const int row  = blockIdx.x * 4 + (threadIdx.x >> 6);
  const int lane = threadIdx.x & 63;
  u16* p; const float* nw; float sc; int s;
  if (row < S_LEN*NHEADS) {
    p = Qb + (long)row * HD; nw = qw; sc = 0.08838834764831845f; s = row >> 5;
  } else {
    const int r2 = row - S_LEN*NHEADS;
    p = Kb + (long)r2 * HD; nw = kw; sc = 1.0f; s = r2 >> 3;
  }

  float x1 = __uint_as_float(((unsigned)p[lane]) << 16);
  float x2 = __uint_as_float(((unsigned)p[lane + 64]) << 16);
  float ss = x1*x1 + x2*x2;
  #pragma unroll
  for (int m = 32; m >= 1; m >>= 1) ss += __shfl_xor(ss, m);
  const float inv = rsqrtf(ss * (1.0f/128.0f) + 1e-6f);
  x1 *= inv * nw[lane];
  x2 *= inv * nw[lane + 64];

  const float inv_freq = expf(-(float)lane * (13.815510557964274f / 64.0f));
  const float ang = (float)pos[s] * inv_freq;
  float sn, cs;
  sincosf(ang, &sn, &cs);
  p[lane]      = f2bf((x1*cs - x2*sn) * sc);
  p[lane + 64] = f2bf((x2*cs + x1*sn) * sc);
}

// ---------------------------------------------------------------------------
// Causal flash attention, one q-tile (64 rows) per block, 4 waves x 16 rows.
// EXACT round-1 version (measured 130.5 us): 40KB LDS x 4 blocks/CU,
// VGPR<=128 (lb 256,4) -> 16 waves/CU. Defer-max (T13), setprio (T5).
// grid (32, heads); T = 31-((x+y)&31) balances per-CU work.
// ---------------------------------------------------------------------------
__global__ __launch_bounds__(256, 4) void attn(
    const u16* __restrict__ Q, const u16* __restrict__ K,
    const u16* __restrict__ VT, u16* __restrict__ O)
{
  __shared__ u16 Ks[64*128];   // [kv][d], XOR-swizzled cols
  __shared__ u16 Vt[128*64];   // [d][kv], XOR-swizzled cols
  __shared__ u16 Ps[4*16*64];  // per-wave P tile

  const int tid  = threadIdx.x;
  const int lane = tid & 63;
  const int w    = tid >> 6;
  const int l16  = lane & 15, lhi = lane >> 4;
  const int h    = blockIdx.y;
  const int kh   = h >> 2;               // GQA 4:1
  const int T    = (NT - 1) - ((blockIdx.x + blockIdx.y) & (NT - 1));
  const int qrow0 = T*64 + w*16;

  bf16x8 qf[4];
  #pragma unroll
  for (int ks = 0; ks < 4; ++ks)
    qf[ks] = *(const bf16x8*)(Q + (long)(qrow0 + l16)*QDIM + h*HD + ks*32 + lhi*8);

  float mr[4] = {-1e30f,-1e30f,-1e30f,-1e30f};
  float lr[4] = {0.f,0.f,0.f,0.f};
  f32x4 of[8] = {};
  u16* Pw = Ps + w*16*64;

  for (int t = 0; t <= T; ++t) {
    const int kv0 = t * 64;
    // stage K tile [64][128]
    #pragma unroll
    for (int i = 0; i < 4; ++i) {
      const int r   = w*16 + i*4 + lhi;
      const int col = (l16*8) ^ ((r & 7) << 3);
      lds_load16(K + (long)(kv0 + r)*KVDIM + kh*HD + col,
                 Ks + (w*16 + i*4)*128);
    }
    // stage V^T tile [128][64]
    #pragma unroll
    for (int i = 0; i < 4; ++i) {
      const int r   = w*32 + i*8 + (lane >> 3);
      const int col = ((lane & 7)*8) ^ ((r & 7) << 3);
      lds_load16(VT + (long)(kh*HD + r)*S_LEN + kv0 + col,
                 Vt + (w*32 + i*8)*64);
    }
    __syncthreads();

    // ---- QK^T ----
    f32x4 sa[4] = {};
    __builtin_amdgcn_s_setprio(1);
    #pragma unroll
    for (int n = 0; n < 4; ++n)
      #pragma unroll
      for (int ks = 0; ks < 4; ++ks) {
        bf16x8 kf = *(const bf16x8*)(
            Ks + (n*16 + l16)*128 + ((ks*32 + lhi*8) ^ ((l16 & 7) << 3)));
        sa[n] = __builtin_amdgcn_mfma_f32_16x16x32_bf16(qf[ks], kf, sa[n], 0, 0, 0);
      }
    __builtin_amdgcn_s_setprio(0);

    // ---- online softmax, defer-max (THR=8) ----
    const bool diag = (t == T);
    float pm[4];
    #pragma unroll
    for (int r = 0; r < 4; ++r) {
      const int grow = qrow0 + lhi*4 + r;
      #pragma unroll
      for (int n = 0; n < 4; ++n) {
        float sv = sa[n][r];
        if (diag && (kv0 + n*16 + l16 > grow)) sv = -1e9f;
        sa[n][r] = sv;
      }
      float p01 = fmaxf(sa[0][r], sa[1][r]);
      float p23 = fmaxf(sa[2][r], sa[3][r]);
      float pmx = fmaxf(p01, p23);
      pmx = fmaxf(pmx, __shfl_xor(pmx, 1));
      pmx = fmaxf(pmx, __shfl_xor(pmx, 2));
      pmx = fmaxf(pmx, __shfl_xor(pmx, 4));
      pmx = fmaxf(pmx, __shfl_xor(pmx, 8));
      pm[r] = pmx;
    }
    bool need = (pm[0] > mr[0] + 8.f) | (pm[1] > mr[1] + 8.f) |
                (pm[2] > mr[2] + 8.f) | (pm[3] > mr[3] + 8.f);
    if (__any(need)) {
      #pragma unroll
      for (int r = 0; r < 4; ++r) {
        const float mnew  = fmaxf(mr[r], pm[r]);
        const float alpha = __expf(mr[r] - mnew);
        mr[r] = mnew;
        lr[r] *= alpha;
        #pragma unroll
        for (int c = 0; c < 8; ++c) of[c][r] *= alpha;
      }
    }
    #pragma unroll
    for (int r = 0; r < 4; ++r) {
      float rsum = 0.f;
      #pragma unroll
      for (int n = 0; n < 4; ++n) {
        float pv = __expf(sa[n][r] - mr[r]);
        sa[n][r] = pv;
        rsum += pv;
      }
      rsum += __shfl_xor(rsum, 1);
      rsum += __shfl_xor(rsum, 2);
      rsum += __shfl_xor(rsum, 4);
      rsum += __shfl_xor(rsum, 8);
      lr[r] += rsum;
    }

    // ---- P -> LDS, PV ----
    #pragma unroll
    for (int r = 0; r < 4; ++r) {
      const int prow = lhi*4 + r;
      #pragma unroll
      for (int n = 0; n < 4; ++n)
        Pw[prow*64 + ((n*16 + l16) ^ ((prow & 7) << 3))] = f2bf(sa[n][r]);
    }
    __builtin_amdgcn_s_setprio(1);
    #pragma unroll
    for (int ks = 0; ks < 2; ++ks) {
      bf16x8 pf = *(const bf16x8*)(
          Pw + l16*64 + ((ks*32 + lhi*8) ^ ((l16 & 7) << 3)));
      #pragma unroll
      for (int c = 0; c < 8; ++c) {
        bf16x8 vf = *(const bf16x8*)(
            Vt + (c*16 + l16)*64 + ((ks*32 + lhi*8) ^ ((l16 & 7) << 3)));
        of[c] = __builtin_amdgcn_mfma_f32_16x16x32_bf16(pf, vf, of[c], 0, 0, 0);
      }
    }
    __builtin_amdgcn_s_setprio(0);
    __syncthreads();
  }

  #pragma unroll
  for (int r = 0; r < 4; ++r) {
    const float invl = 1.0f / lr[r];
    const long orow = (long)(qrow0 + lhi*4 + r) * QDIM + h*HD;
    #pragma unroll
    for (int c = 0; c < 8; ++c)
      O[orow + c*16 + l16] = f2bf(of[c][r] * invl);
  }
}

// ---------------------------------------------------------------------------
extern "C" void kernel_launch(void* const* d_in, const int* in_sizes, int n_in,
                              void* d_out, int out_size, void* d_ws, size_t ws_size,
                              hipStream_t stream) {
  (void)in_sizes; (void)n_in; (void)out_size; (void)ws_size;
  const float* hs  = (const float*)d_in[0];
  const int*   pos = (const int*)d_in[1];
  const float* Wq  = (const float*)d_in[2];
  const float* Wk  = (const float*)d_in[3];
  const float* Wv  = (const float*)d_in[4];
  const float* Wo  = (const float*)d_in[5];
  const float* qw  = (const float*)d_in[6];
  const float* kw  = (const float*)d_in[7];

  // Workspace layout (bf16 u16 elements), total 88 MB:
  u16* hsB = (u16*)d_ws;                          // 2048*4096
  u16* W1  = hsB + (long)S_LEN*HID;               // 4096*4096 (Wq, later Wo)
  u16* WkB = W1  + (long)QDIM*HID;                // 1024*4096 (contiguous!)
  u16* WvB = WkB + (long)KVDIM*HID;               // 1024*4096 (contiguous!)
  u16* Kb  = WvB + (long)KVDIM*HID;               // 2048*1024
  u16* VT  = Kb  + (long)S_LEN*KVDIM;             // 1024*2048 (V transposed)
  u16* AO  = VT  + (long)KVDIM*S_LEN;             // 2048*4096
  u16* Qb  = (u16*)d_out;                         // 2048*4096 (dead before final GEMM)

  f2b4<<<4096, 256, 0, stream>>>(hs, hsB, (long)S_LEN*HID/8,
                                 Wq, W1,  (long)QDIM*HID/8,
                                 Wk, WkB, (long)KVDIM*HID/8,
                                 Wv, WvB, (long)KVDIM*HID/8);

  // fused Q+K+V projection: B = [Wq; Wk; Wv] (6144 rows), 24x16 = 384 blocks
  gemmFX<3><<<dim3((QDIM+2*KVDIM)/256, S_LEN/128), 512, 0, stream>>>(
      hsB, W1, Qb, Kb, VT, S_LEN, QDIM+2*KVDIM, HID);

  norm_rope2<<<(S_LEN*NHEADS + S_LEN*NKV)/4, 256, 0, stream>>>(
      Qb, Kb, qw, kw, pos);

  f2b<<<2048, 256, 0, stream>>>(Wo, W1, (long)HID*QDIM/8);

  // attention: 32 q-tiles (64 rows) x 32 heads = 1024 blocks (round-1 proven)
  attn<<<dim3(NT, NHEADS), 256, 0, stream>>>(Qb, Kb, VT, AO);

  // final projection: 128x256 tile, 16x16 = 256 blocks (full machine)
  gemmFX<1><<<dim3(HID/256, S_LEN/128), 512, 0, stream>>>(
      AO, W1, d_out, nullptr, nullptr, S_LEN, HID, QDIM);
}